// Round 4
// baseline (72.861 us; speedup 1.0000x reference)
//
#include <hip/hip_runtime.h>
#include <math.h>

// Hyp_plus_MLR closed form (all reductions along a_hat = z_k/||z_k||):
//   ts=sign(r)tanh(|r|*||z||), an=||z||/cosh^2 r, w=(y.z)/||z||
//   xy=-ts*w, x2=ts^2, A=1+2xy+y2, Bc=1-x2, den=1+2xy+x2*y2
//   |m|^2=(A^2 x2+2ABc xy+Bc^2 y2)/den^2, m.a_hat=(Bc w-A ts)/den
//   out[b,k] = 2*an*asinh((m.a_hat)*2/(1-|m|^2))
//
// Grid 256 blocks x 256 thr. Block = 8 rows x all 128 k, full Z in LDS
// (138 KB static LDS compiles+launches on gfx950 — verified R3).
// Thread = (k, d-half): 8 rows x 1 k x 128 d -> 8x z-reuse per LDS read,
// VALU-bound inner loop (36 fmac = 72 cyc vs 1 ds_read_b128 = 12 cyc per j).
// y loads wave-uniform (rows block-uniform, d-half readfirstlane) -> s_load.
// R3 bug fixed here: staging map is r = idx>>6, q = idx&63 (64 quads/row),
// NOT the 16-quad chunk map — that one wrote LDS out of bounds.

#define D_DIM 256
#define K_DIM 128
#define ZS    260   // z row stride (floats); %32==4 -> phase-disjoint b128 reads
#define ROWS  8

__global__ __launch_bounds__(256) void hyp_mlr_kernel(
    const float* __restrict__ Y,   // (2048,256)
    const float* __restrict__ Z,   // (128,256)
    const float* __restrict__ R,   // (128,1)
    float* __restrict__ out)       // (2048,128)
{
  __shared__ float zt[K_DIM * ZS];   // 133,120 B: full Z, padded rows
  __shared__ float part[K_DIM][11];  // half-1 partials (8 dots + nz2), pad 11
  __shared__ float sy2[ROWS];

  const int t    = threadIdx.x;
  const int lane = t & 63;
  const int wv   = __builtin_amdgcn_readfirstlane(threadIdx.x >> 6); // 0..3
  const int half = wv >> 1;                 // uniform d-half
  const int k    = lane + ((wv & 1) << 6);  // 0..127
  const int b0   = blockIdx.x * ROWS;
  const float* __restrict__ yb = Y + (size_t)b0 * D_DIM;  // block-uniform

  // ---- stage full Z -> LDS: 8192 float4, 64 quads per 256-float row ----
  // (each wave-instruction covers one contiguous 1 KB Z row: fully coalesced)
  #pragma unroll
  for (int i = 0; i < 32; ++i) {
    int idx = t + i * 256;
    int r = idx >> 6, q = idx & 63;          // FIXED mapping (was >>4 / &15)
    float4 v = *(const float4*)(Z + r * D_DIM + q * 4);
    *(float4*)&zt[r * ZS + q * 4] = v;
  }

  // ---- y2 for rows 2wv, 2wv+1 (coalesced + wave butterfly) ----
  {
    float4 u0 = *(const float4*)(yb + (2 * wv) * D_DIM + lane * 4);
    float4 u1 = *(const float4*)(yb + (2 * wv + 1) * D_DIM + lane * 4);
    float s0 = u0.x*u0.x + u0.y*u0.y + u0.z*u0.z + u0.w*u0.w;
    float s1 = u1.x*u1.x + u1.y*u1.y + u1.z*u1.z + u1.w*u1.w;
    #pragma unroll
    for (int off = 32; off > 0; off >>= 1) {
      s0 += __shfl_xor(s0, off);
      s1 += __shfl_xor(s1, off);
    }
    if (lane == 0) { sy2[2 * wv] = s0; sy2[2 * wv + 1] = s1; }
  }

  __syncthreads();

  // ---- main loop: 8 rows x 1 k over this thread's 128-d half ----
  const float* zp = &zt[k * ZS + half * 128];
  const float* yp = yb + half * 128;
  float acc[ROWS] = {0.f, 0.f, 0.f, 0.f, 0.f, 0.f, 0.f, 0.f};
  float nzp = 0.f;
  #pragma unroll 4
  for (int j = 0; j < 32; ++j) {
    float4 z = *(const float4*)(zp + 4 * j);
    nzp = fmaf(z.x, z.x, nzp); nzp = fmaf(z.y, z.y, nzp);
    nzp = fmaf(z.z, z.z, nzp); nzp = fmaf(z.w, z.w, nzp);
    #pragma unroll
    for (int r = 0; r < ROWS; ++r) {
      float4 yv = *(const float4*)(yp + r * D_DIM + 4 * j);  // wave-uniform
      acc[r] = fmaf(yv.x, z.x, acc[r]);
      acc[r] = fmaf(yv.y, z.y, acc[r]);
      acc[r] = fmaf(yv.z, z.z, acc[r]);
      acc[r] = fmaf(yv.w, z.w, acc[r]);
    }
  }

  // ---- half-1 threads export partials; half-0 threads own k=t ----
  if (t >= 128) {
    #pragma unroll
    for (int r = 0; r < ROWS; ++r) part[t - 128][r] = acc[r];
    part[t - 128][8] = nzp;
  }
  __syncthreads();

  if (t < K_DIM) {
    float nz2 = nzp + part[t][8];
    float nz = sqrtf(nz2);
    float rr = R[t];
    float un = fmaxf(fabsf(rr) * nz, 1e-15f);
    float ts = copysignf(tanhf(un), rr);
    float ch = coshf(rr);
    float inv_nz = 1.f / fmaxf(nz, 1e-30f);
    float an2 = 2.f * nz / (ch * ch);
    float x2 = ts * ts;
    #pragma unroll
    for (int r = 0; r < ROWS; ++r) {
      float w  = (acc[r] + part[t][r]) * inv_nz;  // y . a_hat
      float y2 = sy2[r];
      float xy = -ts * w;
      float A   = 1.f + 2.f * xy + y2;
      float Bc  = 1.f - x2;
      float den = 1.f + 2.f * xy + x2 * y2;
      float invden = 1.f / den;
      float mm  = (A*A*x2 + 2.f*A*Bc*xy + Bc*Bc*y2) * invden * invden;
      float lam = 2.f / (1.f - mm);
      float ma  = (Bc * w - A * ts) * invden;     // m . a_hat
      out[(b0 + r) * K_DIM + t] = an2 * asinhf(ma * lam);
    }
  }
}

extern "C" void kernel_launch(void* const* d_in, const int* in_sizes, int n_in,
                              void* d_out, int out_size, void* d_ws, size_t ws_size,
                              hipStream_t stream) {
  const float* Y = (const float*)d_in[0];
  const float* Z = (const float*)d_in[1];
  const float* R = (const float*)d_in[2];
  float* out = (float*)d_out;
  hipLaunchKernelGGL(hyp_mlr_kernel, dim3(2048 / ROWS), dim3(256), 0, stream,
                     Y, Z, R, out);
}

// Round 5
// 66.374 us; speedup vs baseline: 1.0977x; 1.0977x over previous
//
#include <hip/hip_runtime.h>
#include <math.h>

// Hyp_plus_MLR closed form (all reductions along a_hat = z_k/||z_k||):
//   ts=sign(r)tanh(|r|*||z||), an=||z||/cosh^2 r, w=(y.z)/||z||
//   xy=-ts*w, x2=ts^2, A=1+2xy+y2, Bc=1-x2, den=1+2xy+x2*y2
//   |m|^2=(A^2 x2+2ABc xy+Bc^2 y2)/den^2, m.a_hat=(Bc w-A ts)/den
//   out[b,k] = 2*an*asinh((m.a_hat)*2/(1-|m|^2))
//
// R4 lesson: latency-bound, not throughput-bound — waves/SIMD dominates.
// Grid 256 blocks x 512 threads (8 waves = 2/SIMD). Thread = (k, d-quarter):
// 8 rows x 1 k x 64 d. Z fragment global->VGPR direct (no LDS staging, no
// staging barrier; 128 KB/CU from L2). Y via fully-uniform addresses ->
// scalar-cache s_load. One LDS exchange (18 KB) + ONE barrier total.

#define D_DIM 256
#define K_DIM 128
#define ROWS  8
#define PSTR  12   // partial row stride (floats); 3 quads, coprime phase -> free

__global__ __launch_bounds__(512) void hyp_mlr_kernel(
    const float* __restrict__ Y,   // (2048,256)
    const float* __restrict__ Z,   // (128,256)
    const float* __restrict__ R,   // (128,1)
    float* __restrict__ out)       // (2048,128)
{
  __shared__ float part[3 * K_DIM * PSTR];  // quarters 1..3: 8 accs + nz2
  __shared__ float sy2[ROWS];

  const int t    = threadIdx.x;
  const int lane = t & 63;
  const int wv   = __builtin_amdgcn_readfirstlane(threadIdx.x >> 6); // 0..7
  const int q    = wv >> 1;                  // uniform d-quarter 0..3
  const int k    = lane + ((wv & 1) << 6);   // 0..127
  const int b0   = blockIdx.x * ROWS;
  const float* __restrict__ yb = Y + (size_t)b0 * D_DIM;  // block-uniform

  // ---- z fragment: 64 floats global -> VGPR (issue first, longest latency) ----
  float4 zr[16];
  {
    const float* zp = Z + k * D_DIM + q * 64;
    #pragma unroll
    for (int i = 0; i < 16; ++i) zr[i] = *(const float4*)(zp + 4 * i);
  }

  // ---- y2: wave wv owns row wv (coalesced + 64-lane butterfly) ----
  {
    const float* yr = yb + wv * D_DIM;
    float4 u = *(const float4*)(yr + lane * 4);
    float s = u.x*u.x + u.y*u.y + u.z*u.z + u.w*u.w;
    #pragma unroll
    for (int off = 32; off > 0; off >>= 1) s += __shfl_xor(s, off);
    if (lane == 0) sy2[wv] = s;
  }

  // ---- nz2 partial over this quarter ----
  float nzp = 0.f;
  #pragma unroll
  for (int i = 0; i < 16; ++i) {
    nzp = fmaf(zr[i].x, zr[i].x, nzp); nzp = fmaf(zr[i].y, zr[i].y, nzp);
    nzp = fmaf(zr[i].z, zr[i].z, nzp); nzp = fmaf(zr[i].w, zr[i].w, nzp);
  }

  // ---- main loop: 8 rows, y uniform -> s_load, z from VGPRs ----
  float acc[ROWS];
  const float* yq = yb + q * 64;
  #pragma unroll
  for (int r = 0; r < ROWS; ++r) {
    const float* yr = yq + r * D_DIM;
    float a = 0.f;
    #pragma unroll
    for (int i = 0; i < 16; ++i) {
      float4 yv = *(const float4*)(yr + 4 * i);   // uniform -> scalar cache
      a = fmaf(yv.x, zr[i].x, a);
      a = fmaf(yv.y, zr[i].y, a);
      a = fmaf(yv.z, zr[i].z, a);
      a = fmaf(yv.w, zr[i].w, a);
    }
    acc[r] = a;
  }

  // ---- quarters 1..3 export partials; ONE barrier ----
  if (q > 0) {
    float* p = &part[((q - 1) * K_DIM + k) * PSTR];
    #pragma unroll
    for (int r = 0; r < ROWS; ++r) p[r] = acc[r];
    p[8] = nzp;
  }
  __syncthreads();

  // ---- quarter-0 threads (t == k < 128) finalize ----
  if (t < K_DIM) {
    float nz2 = nzp;
    #pragma unroll
    for (int qq = 0; qq < 3; ++qq) {
      const float* p = &part[(qq * K_DIM + t) * PSTR];
      #pragma unroll
      for (int r = 0; r < ROWS; ++r) acc[r] += p[r];
      nz2 += p[8];
    }
    float nz = sqrtf(nz2);
    float rr = R[t];
    float un = fmaxf(fabsf(rr) * nz, 1e-15f);    // EPS clamp, matches ref
    float ts = copysignf(tanhf(un), rr);
    float ch = coshf(rr);
    float inv_nz = 1.f / fmaxf(nz, 1e-30f);
    float an2 = 2.f * nz / (ch * ch);
    float x2 = ts * ts;
    #pragma unroll
    for (int r = 0; r < ROWS; ++r) {
      float w  = acc[r] * inv_nz;                // y . a_hat
      float y2 = sy2[r];
      float xy = -ts * w;
      float A   = 1.f + 2.f * xy + y2;
      float Bc  = 1.f - x2;
      float den = 1.f + 2.f * xy + x2 * y2;
      float invden = 1.f / den;
      float mm  = (A*A*x2 + 2.f*A*Bc*xy + Bc*Bc*y2) * invden * invden;
      float lam = 2.f / (1.f - mm);
      float ma  = (Bc * w - A * ts) * invden;    // m . a_hat
      out[(b0 + r) * K_DIM + t] = an2 * asinhf(ma * lam);
    }
  }
}

extern "C" void kernel_launch(void* const* d_in, const int* in_sizes, int n_in,
                              void* d_out, int out_size, void* d_ws, size_t ws_size,
                              hipStream_t stream) {
  const float* Y = (const float*)d_in[0];
  const float* Z = (const float*)d_in[1];
  const float* R = (const float*)d_in[2];
  float* out = (float*)d_out;
  hipLaunchKernelGGL(hyp_mlr_kernel, dim3(2048 / ROWS), dim3(512), 0, stream,
                     Y, Z, R, out);
}

// Round 6
// 65.466 us; speedup vs baseline: 1.1130x; 1.0139x over previous
//
#include <hip/hip_runtime.h>
#include <math.h>

// Hyp_plus_MLR closed form (all reductions along a_hat = z_k/||z_k||):
//   ts=sign(r)tanh(|r|*||z||), an=||z||/cosh^2 r, w=(y.z)/||z||
//   xy=-ts*w, x2=ts^2, A=1+2xy+y2, Bc=1-x2, den=1+2xy+x2*y2
//   |m|^2=(A^2 x2+2ABc xy+Bc^2 y2)/den^2, m.a_hat=(Bc w-A ts)/den
//   out[b,k] = 2*an*asinh((m.a_hat)*2/(1-|m|^2))
//
// R5 lesson: direct global z-gather (lane->k, 1 KB lane stride) costs ~64
// line-transactions per load instr (~3.4 us/CU of TA serialization). Fix:
// coalesced global->LDS staging of full Z, LDS as the transposer. Grid is
// 256 blocks = 1 block/CU regardless, so 151 KB LDS costs NO occupancy:
// still 512 thr = 8 waves/CU = 2/SIMD (R4's mistake was 4-wave blocks).
// Thread = (k, d-quarter): 8 rows x 1 k x 64 d, z fragment LDS->VGPR
// (stride 260 floats => bank-quad = k+16q+j mod 32: exact 2-way alias, free).
// y loads fully uniform -> scalar cache. 2 barriers total.

#define D_DIM 256
#define K_DIM 128
#define ZS    260   // z row stride in floats (65 quads, 65 = 1 mod 32)
#define ROWS  8
#define PSTR  12    // partial row stride (floats)

__global__ __launch_bounds__(512) void hyp_mlr_kernel(
    const float* __restrict__ Y,   // (2048,256)
    const float* __restrict__ Z,   // (128,256)
    const float* __restrict__ R,   // (128,1)
    float* __restrict__ out)       // (2048,128)
{
  __shared__ float zt[K_DIM * ZS];          // 133,120 B: full Z, padded rows
  __shared__ float part[3 * K_DIM * PSTR];  // 18,432 B: quarters 1..3 partials
  __shared__ float sy2[ROWS];

  const int t    = threadIdx.x;
  const int lane = t & 63;
  const int wv   = __builtin_amdgcn_readfirstlane(threadIdx.x >> 6); // 0..7
  const int qd   = wv >> 1;                  // uniform d-quarter 0..3
  const int k    = lane + ((wv & 1) << 6);   // 0..127
  const int b0   = blockIdx.x * ROWS;
  const float* __restrict__ yb = Y + (size_t)b0 * D_DIM;  // block-uniform

  // ---- stage full Z -> LDS, coalesced: 8192 float4, 16 per thread ----
  // idx consecutive within a wave => each instr covers one contiguous 1 KB
  // Z row (8 txn) and one contiguous LDS row (no bank conflicts).
  #pragma unroll
  for (int i = 0; i < 16; ++i) {
    int idx = t + i * 512;
    int r = idx >> 6, q = idx & 63;          // 64 quads per 256-float row
    float4 v = *(const float4*)(Z + r * D_DIM + q * 4);
    *(float4*)&zt[r * ZS + q * 4] = v;
  }

  // ---- y2: wave wv owns row wv (coalesced + 64-lane butterfly) ----
  {
    const float* yr = yb + wv * D_DIM;
    float4 u = *(const float4*)(yr + lane * 4);
    float s = u.x*u.x + u.y*u.y + u.z*u.z + u.w*u.w;
    #pragma unroll
    for (int off = 32; off > 0; off >>= 1) s += __shfl_xor(s, off);
    if (lane == 0) sy2[wv] = s;
  }

  __syncthreads();

  // ---- z fragment LDS -> VGPR: 16 ds_read_b128, 2-way bank alias (free) ----
  float4 zr[16];
  {
    const float* zp = &zt[k * ZS + qd * 64];
    #pragma unroll
    for (int i = 0; i < 16; ++i) zr[i] = *(const float4*)(zp + 4 * i);
  }

  // ---- nz2 partial over this quarter ----
  float nzp = 0.f;
  #pragma unroll
  for (int i = 0; i < 16; ++i) {
    nzp = fmaf(zr[i].x, zr[i].x, nzp); nzp = fmaf(zr[i].y, zr[i].y, nzp);
    nzp = fmaf(zr[i].z, zr[i].z, nzp); nzp = fmaf(zr[i].w, zr[i].w, nzp);
  }

  // ---- main loop: 8 rows, y uniform -> s_load, z from VGPRs ----
  float acc[ROWS];
  const float* yq = yb + qd * 64;
  #pragma unroll
  for (int r = 0; r < ROWS; ++r) {
    const float* yr = yq + r * D_DIM;
    float a = 0.f;
    #pragma unroll
    for (int i = 0; i < 16; ++i) {
      float4 yv = *(const float4*)(yr + 4 * i);   // uniform -> scalar cache
      a = fmaf(yv.x, zr[i].x, a);
      a = fmaf(yv.y, zr[i].y, a);
      a = fmaf(yv.z, zr[i].z, a);
      a = fmaf(yv.w, zr[i].w, a);
    }
    acc[r] = a;
  }

  // ---- quarters 1..3 export partials ----
  if (qd > 0) {
    float* p = &part[((qd - 1) * K_DIM + k) * PSTR];
    #pragma unroll
    for (int r = 0; r < ROWS; ++r) p[r] = acc[r];
    p[8] = nzp;
  }
  __syncthreads();

  // ---- quarter-0 threads (t == k < 128) finalize ----
  if (t < K_DIM) {
    float nz2 = nzp;
    #pragma unroll
    for (int qq = 0; qq < 3; ++qq) {
      const float* p = &part[(qq * K_DIM + t) * PSTR];
      #pragma unroll
      for (int r = 0; r < ROWS; ++r) acc[r] += p[r];
      nz2 += p[8];
    }
    float nz = sqrtf(nz2);
    float rr = R[t];
    float un = fmaxf(fabsf(rr) * nz, 1e-15f);    // EPS clamp, matches ref
    float ts = copysignf(tanhf(un), rr);
    float ch = coshf(rr);
    float inv_nz = 1.f / fmaxf(nz, 1e-30f);
    float an2 = 2.f * nz / (ch * ch);
    float x2 = ts * ts;
    #pragma unroll
    for (int r = 0; r < ROWS; ++r) {
      float w  = acc[r] * inv_nz;                // y . a_hat
      float y2 = sy2[r];
      float xy = -ts * w;
      float A   = 1.f + 2.f * xy + y2;
      float Bc  = 1.f - x2;
      float den = 1.f + 2.f * xy + x2 * y2;
      float invden = 1.f / den;
      float mm  = (A*A*x2 + 2.f*A*Bc*xy + Bc*Bc*y2) * invden * invden;
      float lam = 2.f / (1.f - mm);
      float ma  = (Bc * w - A * ts) * invden;    // m . a_hat
      out[(b0 + r) * K_DIM + t] = an2 * asinhf(ma * lam);
    }
  }
}

extern "C" void kernel_launch(void* const* d_in, const int* in_sizes, int n_in,
                              void* d_out, int out_size, void* d_ws, size_t ws_size,
                              hipStream_t stream) {
  const float* Y = (const float*)d_in[0];
  const float* Z = (const float*)d_in[1];
  const float* R = (const float*)d_in[2];
  float* out = (float*)d_out;
  hipLaunchKernelGGL(hyp_mlr_kernel, dim3(2048 / ROWS), dim3(512), 0, stream,
                     Y, Z, R, out);
}

// Round 7
// 63.118 us; speedup vs baseline: 1.1544x; 1.0372x over previous
//
#include <hip/hip_runtime.h>
#include <math.h>

// Hyp_plus_MLR closed form (all reductions along a_hat = z_k/||z_k||):
//   ts=sign(r)tanh(|r|*||z||), an=||z||/cosh^2 r, w=(y.z)/||z||
//   xy=-ts*w, x2=ts^2, A=1+2xy+y2, Bc=1-x2, den=1+2xy+x2*y2
//   |m|^2=(A^2 x2+2ABc xy+Bc^2 y2)/den^2, m.a_hat=(Bc w-A ts)/den
//   out[b,k] = 2*an*asinh((m.a_hat)*2/(1-|m|^2))
//
// R6 -> R7: same dataflow (coalesced Z->LDS, LDS as transposer, y via
// scalar cache), but 1024 threads/block (16 waves = 4/SIMD; grid is
// 1 block/CU either way so 148 KB LDS costs no occupancy) and a flat
// epilogue: 1024 threads = 8 rows x 128 k = ONE output element each
// (R6 ran the tail on 128/512 threads x 8 serial transcendental chains).
// Thread = (k, d-quarter, row-half): 4 rows x 1 k x 64 d, z in two
// 8-float4 sub-chunks to cap VGPR (~60 << 128 needed for 16 waves/CU).

#define D_DIM 256
#define K_DIM 128
#define ZS    260   // z row stride (floats): bank-quad (k + c) mod 32 -> 2-way, free
#define ROWS  8

__global__ __launch_bounds__(1024) void hyp_mlr_kernel(
    const float* __restrict__ Y,   // (2048,256)
    const float* __restrict__ Z,   // (128,256)
    const float* __restrict__ R,   // (128,1)
    float* __restrict__ out)       // (2048,128)
{
  __shared__ float zt[K_DIM * ZS];           // 133,120 B: full Z, padded rows
  __shared__ float part4[4 * K_DIM * 2 * 4]; // 16,384 B: [q][k][half] float4 accs
  __shared__ float nzq[4 * K_DIM];           //  2,048 B: [q][k] nz2 partials
  __shared__ float sy2[ROWS];

  const int t    = threadIdx.x;
  const int lane = t & 63;
  const int wv   = __builtin_amdgcn_readfirstlane(threadIdx.x >> 6); // 0..15
  const int qd   = (wv >> 1) & 3;            // uniform d-quarter
  const int h    = wv >> 3;                  // uniform row-half
  const int k    = lane + ((wv & 1) << 6);   // 0..127
  const int b0   = blockIdx.x * ROWS;
  const float* __restrict__ yb = Y + (size_t)b0 * D_DIM;  // block-uniform

  // ---- stage full Z -> LDS, coalesced: 8192 float4, 8 per thread ----
  // each wave-instruction covers one contiguous 1 KB Z row / LDS row.
  #pragma unroll
  for (int i = 0; i < 8; ++i) {
    int idx = t + i * 1024;
    int r = idx >> 6, q = idx & 63;
    float4 v = *(const float4*)(Z + r * D_DIM + q * 4);
    *(float4*)&zt[r * ZS + q * 4] = v;
  }

  // ---- y2: waves 0..7 own row wv (coalesced + 64-lane butterfly) ----
  if (wv < ROWS) {
    const float* yr = yb + wv * D_DIM;
    float4 u = *(const float4*)(yr + lane * 4);
    float s = u.x*u.x + u.y*u.y + u.z*u.z + u.w*u.w;
    #pragma unroll
    for (int off = 32; off > 0; off >>= 1) s += __shfl_xor(s, off);
    if (lane == 0) sy2[wv] = s;
  }

  __syncthreads();

  // ---- main: 4 rows x 1 k x 64 d, two 32-float sub-chunks ----
  float acc[4] = {0.f, 0.f, 0.f, 0.f};
  float nzp = 0.f;
  const float* zp = &zt[k * ZS + qd * 64];
  const float* yq = yb + qd * 64 + h * 4 * D_DIM;
  #pragma unroll
  for (int sub = 0; sub < 2; ++sub) {
    float4 zr[8];
    #pragma unroll
    for (int i = 0; i < 8; ++i) zr[i] = *(const float4*)(zp + sub * 32 + 4 * i);
    #pragma unroll
    for (int i = 0; i < 8; ++i) {
      nzp = fmaf(zr[i].x, zr[i].x, nzp); nzp = fmaf(zr[i].y, zr[i].y, nzp);
      nzp = fmaf(zr[i].z, zr[i].z, nzp); nzp = fmaf(zr[i].w, zr[i].w, nzp);
    }
    #pragma unroll
    for (int r = 0; r < 4; ++r) {
      const float* yr = yq + r * D_DIM + sub * 32;
      float a = acc[r];
      #pragma unroll
      for (int i = 0; i < 8; ++i) {
        float4 yv = *(const float4*)(yr + 4 * i);   // uniform -> scalar cache
        a = fmaf(yv.x, zr[i].x, a);
        a = fmaf(yv.y, zr[i].y, a);
        a = fmaf(yv.z, zr[i].z, a);
        a = fmaf(yv.w, zr[i].w, a);
      }
      acc[r] = a;
    }
  }

  // ---- export partials: one b128 per thread; nz2 once per (q,k) ----
  *(float4*)&part4[(((qd * K_DIM + k) * 2 + h) << 2)] =
      make_float4(acc[0], acc[1], acc[2], acc[3]);
  if (h == 0) nzq[qd * K_DIM + k] = nzp;
  __syncthreads();

  // ---- flat epilogue: thread -> one (row, k) output element ----
  {
    const int ke  = t & 127;
    const int row = t >> 7;               // 0..7
    const int hh  = row >> 2, rr = row & 3;
    float a = 0.f, nz2 = 0.f;
    #pragma unroll
    for (int q = 0; q < 4; ++q) {
      a   += part4[(((q * K_DIM + ke) * 2 + hh) << 2) + rr];
      nz2 += nzq[q * K_DIM + ke];
    }
    float nz = sqrtf(nz2);
    float rv = R[ke];                     // lane->ke consecutive: coalesced
    float un = fmaxf(fabsf(rv) * nz, 1e-15f);   // EPS clamp, matches ref
    float ts = copysignf(tanhf(un), rv);
    float ch = coshf(rv);
    float inv_nz = 1.f / fmaxf(nz, 1e-30f);
    float an2 = 2.f * nz / (ch * ch);
    float x2 = ts * ts;
    float w  = a * inv_nz;                // y . a_hat
    float y2 = sy2[row];
    float xy = -ts * w;
    float A   = 1.f + 2.f * xy + y2;
    float Bc  = 1.f - x2;
    float den = 1.f + 2.f * xy + x2 * y2;
    float invden = 1.f / den;
    float mm  = (A*A*x2 + 2.f*A*Bc*xy + Bc*Bc*y2) * invden * invden;
    float lam = 2.f / (1.f - mm);
    float ma  = (Bc * w - A * ts) * invden;     // m . a_hat
    out[(b0 + row) * K_DIM + ke] = an2 * asinhf(ma * lam);
  }
}

extern "C" void kernel_launch(void* const* d_in, const int* in_sizes, int n_in,
                              void* d_out, int out_size, void* d_ws, size_t ws_size,
                              hipStream_t stream) {
  const float* Y = (const float*)d_in[0];
  const float* Z = (const float*)d_in[1];
  const float* R = (const float*)d_in[2];
  float* out = (float*)d_out;
  hipLaunchKernelGGL(hyp_mlr_kernel, dim3(2048 / ROWS), dim3(1024), 0, stream,
                     Y, Z, R, out);
}